// Round 23
// baseline (127.076 us; speedup 1.0000x reference)
//
#include <hip/hip_runtime.h>
#include <hip/hip_bf16.h>
#include <stdint.h>

typedef __bf16 bf16;
typedef __bf16 bf16x4 __attribute__((ext_vector_type(4)));
typedef __bf16 bf16x8 __attribute__((ext_vector_type(8)));
typedef float  f32x4 __attribute__((ext_vector_type(4)));

#define MFMA16(a,b,c) __builtin_amdgcn_mfma_f32_16x16x32_bf16((a),(b),(c),0,0,0)

// async global->LDS, 16B per lane. lds pointer must be wave-uniform; HW adds lane*16.
__device__ __forceinline__ void gld_lds16(const void* g, void* lds_base) {
  __builtin_amdgcn_global_load_lds(
      (const __attribute__((address_space(1))) unsigned int*)g,
      (__attribute__((address_space(3))) unsigned int*)(unsigned int)(uintptr_t)lds_base,
      16, 0, 0);
}

// ---------------- merged prep: cast W_in + transpose x4 + bias_combine --------
struct PrepArgs {
  const float* W_in; bf16* Wib;
  const float* Wsrc[4]; bf16* Wdst[4];
  const float* b_in;
  const float* Wz[3]; const float* bz[3];
  float* bc;
};
__global__ __launch_bounds__(256) void prep_all(PrepArgs a) {
  __shared__ float tile[32][33];
  __shared__ float red[4][64];
  const int bx = blockIdx.x, tid = threadIdx.x;
  if (bx < 512) {
    size_t i = ((size_t)bx * 256 + tid) * 8;
    float4 x = *(const float4*)(a.W_in + i);
    float4 y = *(const float4*)(a.W_in + i + 4);
    bf16x8 o;
    o[0] = (bf16)x.x; o[1] = (bf16)x.y; o[2] = (bf16)x.z; o[3] = (bf16)x.w;
    o[4] = (bf16)y.x; o[5] = (bf16)y.y; o[6] = (bf16)y.z; o[7] = (bf16)y.w;
    *(bf16x8*)(a.Wib + i) = o;
  } else if (bx < 4608) {
    const int idx = bx - 512;
    const int wz = idx >> 10, rem = idx & 1023;
    const int kbase = (rem >> 5) * 32, nbase = (rem & 31) * 32;
    const float* __restrict__ W = a.Wsrc[wz];
    bf16* __restrict__ Wt = a.Wdst[wz];
    const int tx = tid & 31, ty = tid >> 5;  // 32 x 8
#pragma unroll
    for (int i = 0; i < 4; ++i)
      tile[ty + 8 * i][tx] = W[(size_t)(kbase + ty + 8 * i) * 1024 + nbase + tx];
    __syncthreads();
#pragma unroll
    for (int i = 0; i < 4; ++i)
      Wt[(size_t)(nbase + ty + 8 * i) * 1024 + kbase + tx] = (bf16)tile[tx][ty + 8 * i];
  } else {
    const int idx = bx - 4608;
    const int z = idx >> 4, jb = idx & 15;
    const float* W = a.Wz[z];
    const float* ba = a.bz[z];
    const int tj = tid & 63, ti = tid >> 6;
    const int j = jb * 64 + tj;
    float s = 0.f;
#pragma unroll 16
    for (int i = ti * 256; i < ti * 256 + 256; ++i) s += a.b_in[i] * W[(size_t)i * 1024 + j];
    red[ti][tj] = s;
    __syncthreads();
    if (ti == 0)
      a.bc[z * 1024 + j] = ba[j] + red[0][tj] + red[1][tj] + red[2][tj] + red[3][tj];
  }
}

// ---------------- GEMM core: C[M,N] = A[M,K] * Bt[N,K]^T (+bias, *oscale) -----
struct Gemm3 {
  const bf16* A[3];
  const bf16* Bt[3];
  const float* bias[3];
  void* C[3];
  int vtz;          // which z writes transposed output (-1: none)
  bf16* Cvt;        // [N][M] transposed output for z == vtz
  float oscale[3];  // per-z output scale (e.g. fold softmax scale into Q)
};

template <bool OUT_BF16, int BN>
__device__ __forceinline__ void gemm_core(const Gemm3& g, int M, int N, int K, int bx) {
  constexpr int NB = BN / 32;       // 16-col blocks per wave (wave covers BN/2 cols)
  const int nx = N / BN, nyl = (M >> 7) >> 3;
  const int xcd = bx & 7;
  const int ib = bx >> 3;
  const int z = ib / (nx * nyl);
  const int r = ib - z * (nx * nyl);
  const int x = r / nyl;
  const int yl = r - x * nyl;
  const int y = xcd * nyl + yl;

  const bf16* __restrict__ A  = g.A[z];
  const bf16* __restrict__ Bt = g.Bt[z];
  const float* bias = g.bias[z];
  void* C = g.C[z];
  const float osc = g.oscale[z];

  __shared__ bf16 As[128 * 64];
  __shared__ bf16 Bs[BN * 64];

  const int tid = threadIdx.x;
  const int lane = tid & 63;
  const int w = tid >> 6;
  const int wr = w >> 1, wc = w & 1;
  const int l16 = lane & 15, kg = lane >> 4;
  const int m0 = y * 128, n0 = x * BN;

  f32x4 acc[4][NB] = {};

  for (int k0 = 0; k0 < K; k0 += 64) {
#pragma unroll
    for (int i = 0; i < 4; ++i) {
      const int gc = i * 256 + tid;
      const int row = gc >> 3, ch = gc & 7;
      const int lch = ch ^ (row & 7);
      gld_lds16(A + (size_t)(m0 + row) * K + k0 + lch * 8,
                (char*)As + i * 4096 + w * 1024);
    }
#pragma unroll
    for (int i = 0; i < NB; ++i) {
      const int gc = i * 256 + tid;
      const int row = gc >> 3, ch = gc & 7;
      const int lch = ch ^ (row & 7);
      gld_lds16(Bt + (size_t)(n0 + row) * K + k0 + lch * 8,
                (char*)Bs + i * 4096 + w * 1024);
    }
    __syncthreads();
#pragma unroll
    for (int kk = 0; kk < 2; ++kk) {
      const int cc = kk * 4 + kg;
      bf16x8 af[4], bfr[NB];
#pragma unroll
      for (int m = 0; m < 4; ++m) {
        const int rr = wr * 64 + m * 16 + l16;
        af[m] = *(const bf16x8*)((const char*)As + rr * 128 + ((cc ^ (rr & 7)) << 4));
      }
#pragma unroll
      for (int n = 0; n < NB; ++n) {
        const int rn = wc * (BN / 2) + n * 16 + l16;
        bfr[n] = *(const bf16x8*)((const char*)Bs + rn * 128 + ((cc ^ (rn & 7)) << 4));
      }
#pragma unroll
      for (int m = 0; m < 4; ++m)
#pragma unroll
        for (int n = 0; n < NB; ++n)
          acc[m][n] = MFMA16(af[m], bfr[n], acc[m][n]);
    }
    __syncthreads();
  }

  if (z == g.vtz) {
    // transposed write: Cvt[col][row], pack 4 consecutive rows (8B store)
#pragma unroll
    for (int m = 0; m < 4; ++m) {
      const int row0 = m0 + wr * 64 + m * 16 + kg * 4;
#pragma unroll
      for (int n = 0; n < NB; ++n) {
        const int col = n0 + wc * (BN / 2) + n * 16 + l16;
        const float bb = bias ? bias[col] : 0.f;
        bf16x4 pk;
#pragma unroll
        for (int i = 0; i < 4; ++i) pk[i] = (bf16)((acc[m][n][i] + bb) * osc);
        *(bf16x4*)(g.Cvt + (size_t)col * M + row0) = pk;
      }
    }
    return;
  }

#pragma unroll
  for (int m = 0; m < 4; ++m) {
    const int row0 = m0 + wr * 64 + m * 16 + kg * 4;
#pragma unroll
    for (int n = 0; n < NB; ++n) {
      const int col = n0 + wc * (BN / 2) + n * 16 + l16;
      const float bb = bias ? bias[col] : 0.f;
#pragma unroll
      for (int i = 0; i < 4; ++i) {
        float val = (acc[m][n][i] + bb) * osc;
        if (OUT_BF16) ((bf16*)C)[(size_t)(row0 + i) * N + col] = (bf16)val;
        else          ((float*)C)[(size_t)(row0 + i) * N + col] = val;
      }
    }
  }
}

template <bool OUT_BF16, int BN>
__global__ __launch_bounds__(256) void gemm_bt(Gemm3 g, int M, int N, int K) {
  gemm_core<OUT_BF16, BN>(g, M, N, K, blockIdx.x);
}

// ---------------- combine GEMM + q/k/v cast in ONE launch ---------------------
struct CastQKV { const float* src[3]; bf16* dst[3]; };
__global__ __launch_bounds__(256) void combine_cast(Gemm3 g, CastQKV c) {
  if ((int)blockIdx.x < 384) {
    gemm_core<true, 64>(g, 1024, 1024, 1024, blockIdx.x);
  } else {
    const int cb = blockIdx.x - 384;
#pragma unroll
    for (int it = 0; it < 12; ++it) {
      const int chunk = (it * 512 + cb) * 256 + (int)threadIdx.x;  // < 1572864
      const int arr = chunk >> 19;
      const size_t off = (size_t)(chunk & 524287) << 3;
      const float* __restrict__ s = c.src[arr];
      bf16* __restrict__ d = c.dst[arr];
      float4 x = *(const float4*)(s + off);
      float4 y = *(const float4*)(s + off + 4);
      bf16x8 o;
      o[0] = (bf16)x.x; o[1] = (bf16)x.y; o[2] = (bf16)x.z; o[3] = (bf16)x.w;
      o[4] = (bf16)y.x; o[5] = (bf16)y.y; o[6] = (bf16)y.z; o[7] = (bf16)y.w;
      *(bf16x8*)(d + off) = o;
    }
  }
}

// ---------------- flash attention (causal, no-max softmax, packed P) ----------
// R22 structure with SINGLE-BUFFERED K/V: the kernel is dependency-latency
// bound (MfmaUtil 19%, VALU 47%, occ 27.7% at 2 blocks/CU); dropping the
// double-buffer cuts LDS 80K->48K -> 3 blocks/CU (24 waves/CU) so other
// blocks' compute hides this block's staging (m114 wave-level overlap).
// Loop: stage(p); sync; compute both subs; sync.
#define SEQL 2048
__global__ __launch_bounds__(512) void attn_flash(const bf16* __restrict__ qh,
                                                  const bf16* __restrict__ kh,
                                                  const bf16* __restrict__ vt,
                                                  bf16* __restrict__ conc) {
  const int bx = blockIdx.x;
  const int xcd = bx & 7, j = bx >> 3;
  const int half = j >> 5, jj = j & 31;
  const int bh = xcd * 4 + (jj >> 3);
  const int tq = jj & 7;
  const int rb = half ? tq : 15 - tq;
  const int b = bh >> 4, h = bh & 15;
  const int tid = threadIdx.x, lane = tid & 63, w = tid >> 6;
  const int wh = w >> 2;                 // which 64-row half
  const int l16 = lane & 15, kg = lane >> 4;

  __shared__ bf16 KsB[8192];      // 128 rows x 64 elems (swz), 16KB
  __shared__ bf16 VsB[8192];      // 64 d x 128 s (swz), 16KB
  __shared__ bf16 Ps[8 * 1024];   // per-wave 16x64 (swz), shared across subs, 16KB

  char* Psw = (char*)Ps + w * 2048;
  const size_t kvbase = ((size_t)(b * SEQL)) * 1024 + h * 64;
  const bf16* vbase = vt + ((size_t)(h * 64)) * 4096 + b * SEQL;

  auto stage = [&](int p) {
    const int j0 = p * 128;
#pragma unroll
    for (int c = 0; c < 2; ++c) {
      const int idx = c * 512 + tid;
      const int kr = idx >> 3;
      // physical row kr holds key tau(kr): bijective within each 64-group
      const int kkey = (kr & 64) + ((kr & 15) << 2) + ((kr & 63) >> 4);
      const int kch = (idx & 7) ^ (kr & 7);
      gld_lds16(kh + kvbase + (size_t)(j0 + kkey) * 1024 + kch * 8,
                (char*)KsB + c * 8192 + w * 1024);
      const int vr = idx >> 4;
      const int vch = (idx & 15) ^ (vr & 15);
      gld_lds16(vbase + (size_t)vr * 4096 + j0 + vch * 8,
                (char*)VsB + c * 8192 + w * 1024);
    }
  };

  bf16x8 onesv;
#pragma unroll
  for (int i = 0; i < 8; ++i) onesv[i] = (bf16)1.0f;

  const int q0a = rb * 128;
  const int npairs = rb + 1;
  const int myrow0 = q0a + wh * 64 + (w & 3) * 16;  // wave's 16-row base
  const int rowmax = q0a + wh * 64 + 63;            // wave-half's last q row

  const int qrow = myrow0 + l16;
  const size_t qoff = ((size_t)(b * SEQL) + qrow) * 1024 + h * 64;
  const bf16x8 qf0 = *(const bf16x8*)(qh + qoff + kg * 8);
  const bf16x8 qf1 = *(const bf16x8*)(qh + qoff + 32 + kg * 8);

  // hoisted LDS address components (bit-identities verified):
  const int swzk  = (kg ^ (l16 & 7)) << 4;   // K/P swizzle; kb/s-invariant
  const int swzk1 = swzk ^ 64;               // c -> c+4 flips bit 6
  const int swzv  = (kg ^ l16) << 4;         // V swizzle base (rr&15 == l16)
  const char* const pA0 = Psw + l16 * 128 + swzk;    // P-read kc=0
  const char* const pA1 = Psw + l16 * 128 + swzk1;   // P-read kc=1
  const int wsw = (((l16 >> 1) ^ ((kg & 1) * 4)) << 4) | ((l16 & 1) << 3);
  char* wAddr[4];
#pragma unroll
  for (int i = 0; i < 4; ++i)
    wAddr[i] = Psw + kg * 512 + i * 128 + (wsw ^ (i * 16));

  const char* kR0 = (const char*)KsB + l16 * 128 + swzk;
  const char* kR1 = (const char*)KsB + l16 * 128 + swzk1;
  const char* vR  = (const char*)VsB + l16 * 256;

  f32x4 acc[4] = {};
  f32x4 accl = {};

  for (int p = 0; p < npairs; ++p) {
    stage(p);
    __syncthreads();

#pragma unroll
    for (int s = 0; s < 2; ++s) {
      const int j0 = p * 128 + s * 64;
      if (j0 > rowmax) continue;  // sub entirely masked for this wave-half

      // raw scores: 16 q-rows x 64 keys (tile kb, lane l16 -> key 4*l16+kb)
      f32x4 sc[4];
      __builtin_amdgcn_s_setprio(1);
#pragma unroll
      for (int kb = 0; kb < 4; ++kb) {
        bf16x8 kf0 = *(const bf16x8*)(kR0 + s * 8192 + kb * 2048);
        bf16x8 kf1 = *(const bf16x8*)(kR1 + s * 8192 + kb * 2048);
        f32x4 cfr = {};
        cfr = MFMA16(qf0, kf0, cfr);
        sc[kb] = MFMA16(qf1, kf1, cfr);
      }
      __builtin_amdgcn_s_setprio(0);

      if (j0 + 63 > myrow0) {  // tile crosses diagonal for this wave
#pragma unroll
        for (int kb = 0; kb < 4; ++kb) {
          const int key = j0 + l16 * 4 + kb;   // permuted key assignment
#pragma unroll
          for (int i = 0; i < 4; ++i) {
            const int row = myrow0 + kg * 4 + i;
            if (key > row) sc[kb][i] = -1e9f;
          }
        }
      }
      // P = exp2(raw) (scale pre-folded into Q); packed 8B store per row
#pragma unroll
      for (int i = 0; i < 4; ++i) {
        bf16x4 pk;
#pragma unroll
        for (int kb = 0; kb < 4; ++kb)
          pk[kb] = (bf16)__builtin_exp2f(sc[kb][i]);
        *(bf16x4*)(wAddr[i]) = pk;
      }

      // PV: A = P (per-wave LDS), B = V^T rows (LDS); row-sum via ones-MFMA
      __builtin_amdgcn_s_setprio(1);
#pragma unroll
      for (int kc = 0; kc < 2; ++kc) {
        bf16x8 pf = *(const bf16x8*)(kc == 0 ? pA0 : pA1);
        accl = MFMA16(pf, onesv, accl);
        const char* vA = vR + (swzv ^ (s * 128 + kc * 64));
#pragma unroll
        for (int nb = 0; nb < 4; ++nb) {
          bf16x8 vf = *(const bf16x8*)(vA + nb * 4096);
          acc[nb] = MFMA16(pf, vf, acc[nb]);
        }
      }
      __builtin_amdgcn_s_setprio(0);
    }
    __syncthreads();
  }

#pragma unroll
  for (int nb = 0; nb < 4; ++nb)
#pragma unroll
    for (int i = 0; i < 4; ++i) {
      const float val = acc[nb][i] / accl[i];
      const int row = myrow0 + kg * 4 + i;
      conc[((size_t)(b * SEQL) + row) * 1024 + h * 64 + nb * 16 + l16] = (bf16)val;
    }
}

extern "C" void kernel_launch(void* const* d_in, const int* in_sizes, int n_in,
                              void* d_out, int out_size, void* d_ws, size_t ws_size,
                              hipStream_t stream) {
  (void)in_sizes; (void)n_in; (void)out_size; (void)ws_size;
  const float* q    = (const float*)d_in[0];
  const float* k    = (const float*)d_in[1];
  const float* v    = (const float*)d_in[2];
  // d_in[3] = mask (causal by construction; not needed)
  const float* W_in = (const float*)d_in[4];
  const float* b_in = (const float*)d_in[5];
  const float* Wq = (const float*)d_in[6];  const float* bq = (const float*)d_in[7];
  const float* Wk = (const float*)d_in[8];  const float* bk = (const float*)d_in[9];
  const float* Wv = (const float*)d_in[10]; const float* bv = (const float*)d_in[11];
  const float* Wo = (const float*)d_in[12]; const float* bo = (const float*)d_in[13];

  const size_t SA = (size_t)4096 * 1024;  // activation elems
  const size_t SW = (size_t)1024 * 1024;  // weight elems
  bf16* p = (bf16*)d_ws;
  bf16* qb  = p; p += SA;
  bf16* kb  = p; p += SA;
  bf16* vb  = p; p += SA;
  bf16* qhb = p; p += SA;
  bf16* khb = p; p += SA;
  bf16* vhb = p; p += SA;                 // unused (V goes to vtb)
  bf16* Wib = p; p += SW;
  bf16* Wtq = p; p += SW;
  bf16* Wtk = p; p += SW;
  bf16* Wtv = p; p += SW;
  bf16* Wto = p; p += SW;
  bf16* Wc0 = p; p += SW;
  bf16* Wc1 = p; p += SW;
  bf16* Wc2 = p; p += SW;
  float* bc = (float*)p;       // 3 * 1024 fp32
  bf16* conc = qb;             // reuse qb after projections
  bf16* vtb = Wib;             // [1024][4096]; aliases Wib..Wtv (dead after combine GEMM)

  // stage 1: all independent prep in one launch
  PrepArgs pa;
  pa.W_in = W_in; pa.Wib = Wib;
  pa.Wsrc[0] = Wq; pa.Wdst[0] = Wtq;
  pa.Wsrc[1] = Wk; pa.Wdst[1] = Wtk;
  pa.Wsrc[2] = Wv; pa.Wdst[2] = Wtv;
  pa.Wsrc[3] = Wo; pa.Wdst[3] = Wto;
  pa.b_in = b_in;
  pa.Wz[0] = Wq; pa.Wz[1] = Wk; pa.Wz[2] = Wv;
  pa.bz[0] = bq; pa.bz[1] = bk; pa.bz[2] = bv;
  pa.bc = bc;
  prep_all<<<dim3(4656), 256, 0, stream>>>(pa);

  // stage 2: combine weights (Wc_t = (W_in*W)^T) + q/k/v cast, one launch
  Gemm3 gc;
  gc.A[0] = Wtq; gc.A[1] = Wtk; gc.A[2] = Wtv;
  gc.Bt[0] = Wib; gc.Bt[1] = Wib; gc.Bt[2] = Wib;
  gc.bias[0] = nullptr; gc.bias[1] = nullptr; gc.bias[2] = nullptr;
  gc.C[0] = Wc0; gc.C[1] = Wc1; gc.C[2] = Wc2;
  gc.vtz = -1; gc.Cvt = nullptr;
  gc.oscale[0] = 1.f; gc.oscale[1] = 1.f; gc.oscale[2] = 1.f;
  CastQKV cq;
  cq.src[0] = q; cq.src[1] = k; cq.src[2] = v;
  cq.dst[0] = qb; cq.dst[1] = kb; cq.dst[2] = vb;
  combine_cast<<<dim3(896), 256, 0, stream>>>(gc, cq);

  // stage 3: head projections (bf16 A); Q pre-scaled by log2(e)/8 (softmax
  // scale folded in); V written transposed into vtb[1024][4096]
  Gemm3 gp;
  gp.A[0] = qb; gp.A[1] = kb; gp.A[2] = vb;
  gp.Bt[0] = Wc0; gp.Bt[1] = Wc1; gp.Bt[2] = Wc2;
  gp.bias[0] = bc; gp.bias[1] = bc + 1024; gp.bias[2] = bc + 2048;
  gp.C[0] = qhb; gp.C[1] = khb; gp.C[2] = vhb;
  gp.vtz = 2; gp.Cvt = vtb;
  gp.oscale[0] = 0.18033688011112042f;  // log2(e)/8
  gp.oscale[1] = 1.f; gp.oscale[2] = 1.f;
  gemm_bt<true, 128><<<dim3(768), 256, 0, stream>>>(gp, 4096, 1024, 1024);

  attn_flash<<<dim3(512), 512, 0, stream>>>(qhb, khb, vtb, conc);

  // output projection -> fp32 d_out
  Gemm3 gf;
  gf.A[0] = conc; gf.A[1] = conc; gf.A[2] = conc;
  gf.Bt[0] = Wto; gf.Bt[1] = Wto; gf.Bt[2] = Wto;
  gf.bias[0] = bo; gf.bias[1] = bo; gf.bias[2] = bo;
  gf.C[0] = d_out; gf.C[1] = d_out; gf.C[2] = d_out;
  gf.vtz = -1; gf.Cvt = nullptr;
  gf.oscale[0] = 1.f; gf.oscale[1] = 1.f; gf.oscale[2] = 1.f;
  gemm_bt<false, 64><<<dim3(512), 256, 0, stream>>>(gf, 4096, 1024, 1024);
}

// Round 24
// 121.048 us; speedup vs baseline: 1.0498x; 1.0498x over previous
//
#include <hip/hip_runtime.h>
#include <hip/hip_bf16.h>
#include <stdint.h>

typedef __bf16 bf16;
typedef __bf16 bf16x4 __attribute__((ext_vector_type(4)));
typedef __bf16 bf16x8 __attribute__((ext_vector_type(8)));
typedef float  f32x4 __attribute__((ext_vector_type(4)));

#define MFMA16(a,b,c) __builtin_amdgcn_mfma_f32_16x16x32_bf16((a),(b),(c),0,0,0)

// async global->LDS, 16B per lane. lds pointer must be wave-uniform; HW adds lane*16.
__device__ __forceinline__ void gld_lds16(const void* g, void* lds_base) {
  __builtin_amdgcn_global_load_lds(
      (const __attribute__((address_space(1))) unsigned int*)g,
      (__attribute__((address_space(3))) unsigned int*)(unsigned int)(uintptr_t)lds_base,
      16, 0, 0);
}

// ---------------- merged prep: cast W_in + transpose x4 + bias_combine --------
struct PrepArgs {
  const float* W_in; bf16* Wib;
  const float* Wsrc[4]; bf16* Wdst[4];
  const float* b_in;
  const float* Wz[3]; const float* bz[3];
  float* bc;
};
__global__ __launch_bounds__(256) void prep_all(PrepArgs a) {
  __shared__ float tile[32][33];
  __shared__ float red[4][64];
  const int bx = blockIdx.x, tid = threadIdx.x;
  if (bx < 512) {
    size_t i = ((size_t)bx * 256 + tid) * 8;
    float4 x = *(const float4*)(a.W_in + i);
    float4 y = *(const float4*)(a.W_in + i + 4);
    bf16x8 o;
    o[0] = (bf16)x.x; o[1] = (bf16)x.y; o[2] = (bf16)x.z; o[3] = (bf16)x.w;
    o[4] = (bf16)y.x; o[5] = (bf16)y.y; o[6] = (bf16)y.z; o[7] = (bf16)y.w;
    *(bf16x8*)(a.Wib + i) = o;
  } else if (bx < 4608) {
    const int idx = bx - 512;
    const int wz = idx >> 10, rem = idx & 1023;
    const int kbase = (rem >> 5) * 32, nbase = (rem & 31) * 32;
    const float* __restrict__ W = a.Wsrc[wz];
    bf16* __restrict__ Wt = a.Wdst[wz];
    const int tx = tid & 31, ty = tid >> 5;  // 32 x 8
#pragma unroll
    for (int i = 0; i < 4; ++i)
      tile[ty + 8 * i][tx] = W[(size_t)(kbase + ty + 8 * i) * 1024 + nbase + tx];
    __syncthreads();
#pragma unroll
    for (int i = 0; i < 4; ++i)
      Wt[(size_t)(nbase + ty + 8 * i) * 1024 + kbase + tx] = (bf16)tile[tx][ty + 8 * i];
  } else {
    const int idx = bx - 4608;
    const int z = idx >> 4, jb = idx & 15;
    const float* W = a.Wz[z];
    const float* ba = a.bz[z];
    const int tj = tid & 63, ti = tid >> 6;
    const int j = jb * 64 + tj;
    float s = 0.f;
#pragma unroll 16
    for (int i = ti * 256; i < ti * 256 + 256; ++i) s += a.b_in[i] * W[(size_t)i * 1024 + j];
    red[ti][tj] = s;
    __syncthreads();
    if (ti == 0)
      a.bc[z * 1024 + j] = ba[j] + red[0][tj] + red[1][tj] + red[2][tj] + red[3][tj];
  }
}

// ---------------- GEMM core: C[M,N] = A[M,K] * Bt[N,K]^T (+bias, *oscale) -----
struct Gemm3 {
  const bf16* A[3];
  const bf16* Bt[3];
  const float* bias[3];
  void* C[3];
  int vtz;          // which z writes transposed output (-1: none)
  bf16* Cvt;        // [N][M] transposed output for z == vtz
  float oscale[3];  // per-z output scale (e.g. fold softmax scale into Q)
};

template <bool OUT_BF16, int BN>
__device__ __forceinline__ void gemm_core(const Gemm3& g, int M, int N, int K, int bx) {
  constexpr int NB = BN / 32;       // 16-col blocks per wave (wave covers BN/2 cols)
  const int nx = N / BN, nyl = (M >> 7) >> 3;
  const int xcd = bx & 7;
  const int ib = bx >> 3;
  const int z = ib / (nx * nyl);
  const int r = ib - z * (nx * nyl);
  const int x = r / nyl;
  const int yl = r - x * nyl;
  const int y = xcd * nyl + yl;

  const bf16* __restrict__ A  = g.A[z];
  const bf16* __restrict__ Bt = g.Bt[z];
  const float* bias = g.bias[z];
  void* C = g.C[z];
  const float osc = g.oscale[z];

  __shared__ bf16 As[128 * 64];
  __shared__ bf16 Bs[BN * 64];

  const int tid = threadIdx.x;
  const int lane = tid & 63;
  const int w = tid >> 6;
  const int wr = w >> 1, wc = w & 1;
  const int l16 = lane & 15, kg = lane >> 4;
  const int m0 = y * 128, n0 = x * BN;

  f32x4 acc[4][NB] = {};

  for (int k0 = 0; k0 < K; k0 += 64) {
#pragma unroll
    for (int i = 0; i < 4; ++i) {
      const int gc = i * 256 + tid;
      const int row = gc >> 3, ch = gc & 7;
      const int lch = ch ^ (row & 7);
      gld_lds16(A + (size_t)(m0 + row) * K + k0 + lch * 8,
                (char*)As + i * 4096 + w * 1024);
    }
#pragma unroll
    for (int i = 0; i < NB; ++i) {
      const int gc = i * 256 + tid;
      const int row = gc >> 3, ch = gc & 7;
      const int lch = ch ^ (row & 7);
      gld_lds16(Bt + (size_t)(n0 + row) * K + k0 + lch * 8,
                (char*)Bs + i * 4096 + w * 1024);
    }
    __syncthreads();
#pragma unroll
    for (int kk = 0; kk < 2; ++kk) {
      const int cc = kk * 4 + kg;
      bf16x8 af[4], bfr[NB];
#pragma unroll
      for (int m = 0; m < 4; ++m) {
        const int rr = wr * 64 + m * 16 + l16;
        af[m] = *(const bf16x8*)((const char*)As + rr * 128 + ((cc ^ (rr & 7)) << 4));
      }
#pragma unroll
      for (int n = 0; n < NB; ++n) {
        const int rn = wc * (BN / 2) + n * 16 + l16;
        bfr[n] = *(const bf16x8*)((const char*)Bs + rn * 128 + ((cc ^ (rn & 7)) << 4));
      }
#pragma unroll
      for (int m = 0; m < 4; ++m)
#pragma unroll
        for (int n = 0; n < NB; ++n)
          acc[m][n] = MFMA16(af[m], bfr[n], acc[m][n]);
    }
    __syncthreads();
  }

  if (z == g.vtz) {
    // transposed write: Cvt[col][row], pack 4 consecutive rows (8B store)
#pragma unroll
    for (int m = 0; m < 4; ++m) {
      const int row0 = m0 + wr * 64 + m * 16 + kg * 4;
#pragma unroll
      for (int n = 0; n < NB; ++n) {
        const int col = n0 + wc * (BN / 2) + n * 16 + l16;
        const float bb = bias ? bias[col] : 0.f;
        bf16x4 pk;
#pragma unroll
        for (int i = 0; i < 4; ++i) pk[i] = (bf16)((acc[m][n][i] + bb) * osc);
        *(bf16x4*)(g.Cvt + (size_t)col * M + row0) = pk;
      }
    }
    return;
  }

#pragma unroll
  for (int m = 0; m < 4; ++m) {
    const int row0 = m0 + wr * 64 + m * 16 + kg * 4;
#pragma unroll
    for (int n = 0; n < NB; ++n) {
      const int col = n0 + wc * (BN / 2) + n * 16 + l16;
      const float bb = bias ? bias[col] : 0.f;
#pragma unroll
      for (int i = 0; i < 4; ++i) {
        float val = (acc[m][n][i] + bb) * osc;
        if (OUT_BF16) ((bf16*)C)[(size_t)(row0 + i) * N + col] = (bf16)val;
        else          ((float*)C)[(size_t)(row0 + i) * N + col] = val;
      }
    }
  }
}

template <bool OUT_BF16, int BN>
__global__ __launch_bounds__(256) void gemm_bt(Gemm3 g, int M, int N, int K) {
  gemm_core<OUT_BF16, BN>(g, M, N, K, blockIdx.x);
}

// ---------------- combine GEMM + q/k/v cast in ONE launch ---------------------
struct CastQKV { const float* src[3]; bf16* dst[3]; };
__global__ __launch_bounds__(256) void combine_cast(Gemm3 g, CastQKV c) {
  if ((int)blockIdx.x < 384) {
    gemm_core<true, 64>(g, 1024, 1024, 1024, blockIdx.x);
  } else {
    const int cb = blockIdx.x - 384;
#pragma unroll
    for (int it = 0; it < 12; ++it) {
      const int chunk = (it * 512 + cb) * 256 + (int)threadIdx.x;  // < 1572864
      const int arr = chunk >> 19;
      const size_t off = (size_t)(chunk & 524287) << 3;
      const float* __restrict__ s = c.src[arr];
      bf16* __restrict__ d = c.dst[arr];
      float4 x = *(const float4*)(s + off);
      float4 y = *(const float4*)(s + off + 4);
      bf16x8 o;
      o[0] = (bf16)x.x; o[1] = (bf16)x.y; o[2] = (bf16)x.z; o[3] = (bf16)x.w;
      o[4] = (bf16)y.x; o[5] = (bf16)y.y; o[6] = (bf16)y.z; o[7] = (bf16)y.w;
      *(bf16x8*)(d + off) = o;
    }
  }
}

// ---------------- flash attention (causal, no-max softmax, packed P) ----------
// Best measured configuration (R22: 40.6us attn, 121.4us total).
// Structure: 512 thr / 8 waves; ONE 128-row q-block per block; 128-key
// double-buffered iters (two 64-key subs). Packed P-stores via key-interleave
// permutation tau (one ds_write_b64 per row); P = exp2(raw) with softmax scale
// pre-folded into Q by the proj GEMM; all swizzled LDS addresses hoisted.
// Grid 512: xcd=bx&7; rb pairing {tq,15-tq} across halves (co-resident blocks
// balance to 34 tiles/CU); 4 bh per XCD (KV set 2MB < 4MB L2).
#define SEQL 2048
__global__ __launch_bounds__(512) void attn_flash(const bf16* __restrict__ qh,
                                                  const bf16* __restrict__ kh,
                                                  const bf16* __restrict__ vt,
                                                  bf16* __restrict__ conc) {
  const int bx = blockIdx.x;
  const int xcd = bx & 7, j = bx >> 3;
  const int half = j >> 5, jj = j & 31;
  const int bh = xcd * 4 + (jj >> 3);
  const int tq = jj & 7;
  const int rb = half ? tq : 15 - tq;
  const int b = bh >> 4, h = bh & 15;
  const int tid = threadIdx.x, lane = tid & 63, w = tid >> 6;
  const int wh = w >> 2;                 // which 64-row half
  const int l16 = lane & 15, kg = lane >> 4;

  __shared__ bf16 KsB[2 * 8192];  // 2 bufs x 128 rows x 64 elems (swz), 32KB
  __shared__ bf16 VsB[2 * 8192];  // 2 bufs x 64 d x 128 s (swz), 32KB
  __shared__ bf16 Ps[8 * 1024];   // per-wave 16x64 (swz), shared across subs, 16KB

  char* Psw = (char*)Ps + w * 2048;
  const size_t kvbase = ((size_t)(b * SEQL)) * 1024 + h * 64;
  const bf16* vbase = vt + ((size_t)(h * 64)) * 4096 + b * SEQL;

  auto stage = [&](int buf, int p) {
    const int j0 = p * 128;
#pragma unroll
    for (int c = 0; c < 2; ++c) {
      const int idx = c * 512 + tid;
      const int kr = idx >> 3;
      // physical row kr holds key tau(kr): bijective within each 64-group
      const int kkey = (kr & 64) + ((kr & 15) << 2) + ((kr & 63) >> 4);
      const int kch = (idx & 7) ^ (kr & 7);
      gld_lds16(kh + kvbase + (size_t)(j0 + kkey) * 1024 + kch * 8,
                (char*)KsB + buf * 16384 + c * 8192 + w * 1024);
      const int vr = idx >> 4;
      const int vch = (idx & 15) ^ (vr & 15);
      gld_lds16(vbase + (size_t)vr * 4096 + j0 + vch * 8,
                (char*)VsB + buf * 16384 + c * 8192 + w * 1024);
    }
  };

  bf16x8 onesv;
#pragma unroll
  for (int i = 0; i < 8; ++i) onesv[i] = (bf16)1.0f;

  const int q0a = rb * 128;
  const int npairs = rb + 1;
  const int myrow0 = q0a + wh * 64 + (w & 3) * 16;  // wave's 16-row base
  const int rowmax = q0a + wh * 64 + 63;            // wave-half's last q row

  const int qrow = myrow0 + l16;
  const size_t qoff = ((size_t)(b * SEQL) + qrow) * 1024 + h * 64;
  const bf16x8 qf0 = *(const bf16x8*)(qh + qoff + kg * 8);
  const bf16x8 qf1 = *(const bf16x8*)(qh + qoff + 32 + kg * 8);

  // hoisted LDS address components (bit-identities verified):
  const int swzk  = (kg ^ (l16 & 7)) << 4;   // K/P swizzle; kb/s-invariant
  const int swzk1 = swzk ^ 64;               // c -> c+4 flips bit 6
  const int swzv  = (kg ^ l16) << 4;         // V swizzle base (rr&15 == l16)
  const char* const pA0 = Psw + l16 * 128 + swzk;    // P-read kc=0
  const char* const pA1 = Psw + l16 * 128 + swzk1;   // P-read kc=1
  const int wsw = (((l16 >> 1) ^ ((kg & 1) * 4)) << 4) | ((l16 & 1) << 3);
  char* wAddr[4];
#pragma unroll
  for (int i = 0; i < 4; ++i)
    wAddr[i] = Psw + kg * 512 + i * 128 + (wsw ^ (i * 16));

  f32x4 acc[4] = {};
  f32x4 accl = {};

  stage(0, 0);
  __syncthreads();

  for (int p = 0; p < npairs; ++p) {
    const int cur = p & 1;
    if (p + 1 < npairs) stage(cur ^ 1, p + 1);

    const char* Kb = (const char*)KsB + cur * 16384;
    const char* Vb = (const char*)VsB + cur * 16384;
    const char* kR0 = Kb + l16 * 128 + swzk;
    const char* kR1 = Kb + l16 * 128 + swzk1;
    const char* vR  = Vb + l16 * 256;

#pragma unroll
    for (int s = 0; s < 2; ++s) {
      const int j0 = p * 128 + s * 64;
      if (j0 > rowmax) continue;  // sub entirely masked for this wave-half

      // raw scores: 16 q-rows x 64 keys (tile kb, lane l16 -> key 4*l16+kb)
      f32x4 sc[4];
      __builtin_amdgcn_s_setprio(1);
#pragma unroll
      for (int kb = 0; kb < 4; ++kb) {
        bf16x8 kf0 = *(const bf16x8*)(kR0 + s * 8192 + kb * 2048);
        bf16x8 kf1 = *(const bf16x8*)(kR1 + s * 8192 + kb * 2048);
        f32x4 cfr = {};
        cfr = MFMA16(qf0, kf0, cfr);
        sc[kb] = MFMA16(qf1, kf1, cfr);
      }
      __builtin_amdgcn_s_setprio(0);

      if (j0 + 63 > myrow0) {  // tile crosses diagonal for this wave
#pragma unroll
        for (int kb = 0; kb < 4; ++kb) {
          const int key = j0 + l16 * 4 + kb;   // permuted key assignment
#pragma unroll
          for (int i = 0; i < 4; ++i) {
            const int row = myrow0 + kg * 4 + i;
            if (key > row) sc[kb][i] = -1e9f;
          }
        }
      }
      // P = exp2(raw) (scale pre-folded into Q); packed 8B store per row
#pragma unroll
      for (int i = 0; i < 4; ++i) {
        bf16x4 pk;
#pragma unroll
        for (int kb = 0; kb < 4; ++kb)
          pk[kb] = (bf16)__builtin_exp2f(sc[kb][i]);
        *(bf16x4*)(wAddr[i]) = pk;
      }

      // PV: A = P (per-wave LDS), B = V^T rows (LDS); row-sum via ones-MFMA
      __builtin_amdgcn_s_setprio(1);
#pragma unroll
      for (int kc = 0; kc < 2; ++kc) {
        bf16x8 pf = *(const bf16x8*)(kc == 0 ? pA0 : pA1);
        accl = MFMA16(pf, onesv, accl);
        const char* vA = vR + (swzv ^ (s * 128 + kc * 64));
#pragma unroll
        for (int nb = 0; nb < 4; ++nb) {
          bf16x8 vf = *(const bf16x8*)(vA + nb * 4096);
          acc[nb] = MFMA16(pf, vf, acc[nb]);
        }
      }
      __builtin_amdgcn_s_setprio(0);
    }
    __syncthreads();
  }

#pragma unroll
  for (int nb = 0; nb < 4; ++nb)
#pragma unroll
    for (int i = 0; i < 4; ++i) {
      const float val = acc[nb][i] / accl[i];
      const int row = myrow0 + kg * 4 + i;
      conc[((size_t)(b * SEQL) + row) * 1024 + h * 64 + nb * 16 + l16] = (bf16)val;
    }
}

extern "C" void kernel_launch(void* const* d_in, const int* in_sizes, int n_in,
                              void* d_out, int out_size, void* d_ws, size_t ws_size,
                              hipStream_t stream) {
  (void)in_sizes; (void)n_in; (void)out_size; (void)ws_size;
  const float* q    = (const float*)d_in[0];
  const float* k    = (const float*)d_in[1];
  const float* v    = (const float*)d_in[2];
  // d_in[3] = mask (causal by construction; not needed)
  const float* W_in = (const float*)d_in[4];
  const float* b_in = (const float*)d_in[5];
  const float* Wq = (const float*)d_in[6];  const float* bq = (const float*)d_in[7];
  const float* Wk = (const float*)d_in[8];  const float* bk = (const float*)d_in[9];
  const float* Wv = (const float*)d_in[10]; const float* bv = (const float*)d_in[11];
  const float* Wo = (const float*)d_in[12]; const float* bo = (const float*)d_in[13];

  const size_t SA = (size_t)4096 * 1024;  // activation elems
  const size_t SW = (size_t)1024 * 1024;  // weight elems
  bf16* p = (bf16*)d_ws;
  bf16* qb  = p; p += SA;
  bf16* kb  = p; p += SA;
  bf16* vb  = p; p += SA;
  bf16* qhb = p; p += SA;
  bf16* khb = p; p += SA;
  bf16* vhb = p; p += SA;                 // unused (V goes to vtb)
  bf16* Wib = p; p += SW;
  bf16* Wtq = p; p += SW;
  bf16* Wtk = p; p += SW;
  bf16* Wtv = p; p += SW;
  bf16* Wto = p; p += SW;
  bf16* Wc0 = p; p += SW;
  bf16* Wc1 = p; p += SW;
  bf16* Wc2 = p; p += SW;
  float* bc = (float*)p;       // 3 * 1024 fp32
  bf16* conc = qb;             // reuse qb after projections
  bf16* vtb = Wib;             // [1024][4096]; aliases Wib..Wtv (dead after combine GEMM)

  // stage 1: all independent prep in one launch
  PrepArgs pa;
  pa.W_in = W_in; pa.Wib = Wib;
  pa.Wsrc[0] = Wq; pa.Wdst[0] = Wtq;
  pa.Wsrc[1] = Wk; pa.Wdst[1] = Wtk;
  pa.Wsrc[2] = Wv; pa.Wdst[2] = Wtv;
  pa.Wsrc[3] = Wo; pa.Wdst[3] = Wto;
  pa.b_in = b_in;
  pa.Wz[0] = Wq; pa.Wz[1] = Wk; pa.Wz[2] = Wv;
  pa.bz[0] = bq; pa.bz[1] = bk; pa.bz[2] = bv;
  pa.bc = bc;
  prep_all<<<dim3(4656), 256, 0, stream>>>(pa);

  // stage 2: combine weights (Wc_t = (W_in*W)^T) + q/k/v cast, one launch
  Gemm3 gc;
  gc.A[0] = Wtq; gc.A[1] = Wtk; gc.A[2] = Wtv;
  gc.Bt[0] = Wib; gc.Bt[1] = Wib; gc.Bt[2] = Wib;
  gc.bias[0] = nullptr; gc.bias[1] = nullptr; gc.bias[2] = nullptr;
  gc.C[0] = Wc0; gc.C[1] = Wc1; gc.C[2] = Wc2;
  gc.vtz = -1; gc.Cvt = nullptr;
  gc.oscale[0] = 1.f; gc.oscale[1] = 1.f; gc.oscale[2] = 1.f;
  CastQKV cq;
  cq.src[0] = q; cq.src[1] = k; cq.src[2] = v;
  cq.dst[0] = qb; cq.dst[1] = kb; cq.dst[2] = vb;
  combine_cast<<<dim3(896), 256, 0, stream>>>(gc, cq);

  // stage 3: head projections (bf16 A); Q pre-scaled by log2(e)/8 (softmax
  // scale folded in); V written transposed into vtb[1024][4096]
  Gemm3 gp;
  gp.A[0] = qb; gp.A[1] = kb; gp.A[2] = vb;
  gp.Bt[0] = Wc0; gp.Bt[1] = Wc1; gp.Bt[2] = Wc2;
  gp.bias[0] = bc; gp.bias[1] = bc + 1024; gp.bias[2] = bc + 2048;
  gp.C[0] = qhb; gp.C[1] = khb; gp.C[2] = vhb;
  gp.vtz = 2; gp.Cvt = vtb;
  gp.oscale[0] = 0.18033688011112042f;  // log2(e)/8
  gp.oscale[1] = 1.f; gp.oscale[2] = 1.f;
  gemm_bt<true, 128><<<dim3(768), 256, 0, stream>>>(gp, 4096, 1024, 1024);

  attn_flash<<<dim3(512), 512, 0, stream>>>(qhb, khb, vtb, conc);

  // output projection -> fp32 d_out
  Gemm3 gf;
  gf.A[0] = conc; gf.A[1] = conc; gf.A[2] = conc;
  gf.Bt[0] = Wto; gf.Bt[1] = Wto; gf.Bt[2] = Wto;
  gf.bias[0] = bo; gf.bias[1] = bo; gf.bias[2] = bo;
  gf.C[0] = d_out; gf.C[1] = d_out; gf.C[2] = d_out;
  gf.vtz = -1; gf.Cvt = nullptr;
  gf.oscale[0] = 1.f; gf.oscale[1] = 1.f; gf.oscale[2] = 1.f;
  gemm_bt<false, 64><<<dim3(512), 256, 0, stream>>>(gf, 4096, 1024, 1024);
}

// Round 25
// 120.090 us; speedup vs baseline: 1.0582x; 1.0080x over previous
//
#include <hip/hip_runtime.h>
#include <hip/hip_bf16.h>
#include <stdint.h>

typedef __bf16 bf16;
typedef __bf16 bf16x4 __attribute__((ext_vector_type(4)));
typedef __bf16 bf16x8 __attribute__((ext_vector_type(8)));
typedef float  f32x4 __attribute__((ext_vector_type(4)));

#define MFMA16(a,b,c) __builtin_amdgcn_mfma_f32_16x16x32_bf16((a),(b),(c),0,0,0)

// async global->LDS, 16B per lane. lds pointer must be wave-uniform; HW adds lane*16.
__device__ __forceinline__ void gld_lds16(const void* g, void* lds_base) {
  __builtin_amdgcn_global_load_lds(
      (const __attribute__((address_space(1))) unsigned int*)g,
      (__attribute__((address_space(3))) unsigned int*)(unsigned int)(uintptr_t)lds_base,
      16, 0, 0);
}

// ---------------- merged prep: cast W_in + transpose x4 + bias_combine --------
struct PrepArgs {
  const float* W_in; bf16* Wib;
  const float* Wsrc[4]; bf16* Wdst[4];
  const float* b_in;
  const float* Wz[3]; const float* bz[3];
  float* bc;
};
__global__ __launch_bounds__(256) void prep_all(PrepArgs a) {
  __shared__ float tile[32][33];
  __shared__ float red[4][64];
  const int bx = blockIdx.x, tid = threadIdx.x;
  if (bx < 512) {
    size_t i = ((size_t)bx * 256 + tid) * 8;
    float4 x = *(const float4*)(a.W_in + i);
    float4 y = *(const float4*)(a.W_in + i + 4);
    bf16x8 o;
    o[0] = (bf16)x.x; o[1] = (bf16)x.y; o[2] = (bf16)x.z; o[3] = (bf16)x.w;
    o[4] = (bf16)y.x; o[5] = (bf16)y.y; o[6] = (bf16)y.z; o[7] = (bf16)y.w;
    *(bf16x8*)(a.Wib + i) = o;
  } else if (bx < 4608) {
    const int idx = bx - 512;
    const int wz = idx >> 10, rem = idx & 1023;
    const int kbase = (rem >> 5) * 32, nbase = (rem & 31) * 32;
    const float* __restrict__ W = a.Wsrc[wz];
    bf16* __restrict__ Wt = a.Wdst[wz];
    const int tx = tid & 31, ty = tid >> 5;  // 32 x 8
#pragma unroll
    for (int i = 0; i < 4; ++i)
      tile[ty + 8 * i][tx] = W[(size_t)(kbase + ty + 8 * i) * 1024 + nbase + tx];
    __syncthreads();
#pragma unroll
    for (int i = 0; i < 4; ++i)
      Wt[(size_t)(nbase + ty + 8 * i) * 1024 + kbase + tx] = (bf16)tile[tx][ty + 8 * i];
  } else {
    const int idx = bx - 4608;
    const int z = idx >> 4, jb = idx & 15;
    const float* W = a.Wz[z];
    const float* ba = a.bz[z];
    const int tj = tid & 63, ti = tid >> 6;
    const int j = jb * 64 + tj;
    float s = 0.f;
#pragma unroll 16
    for (int i = ti * 256; i < ti * 256 + 256; ++i) s += a.b_in[i] * W[(size_t)i * 1024 + j];
    red[ti][tj] = s;
    __syncthreads();
    if (ti == 0)
      a.bc[z * 1024 + j] = ba[j] + red[0][tj] + red[1][tj] + red[2][tj] + red[3][tj];
  }
}

// ---------------- GEMM core: C[M,N] = A[M,K] * Bt[N,K]^T (+bias, *oscale) -----
struct Gemm3 {
  const bf16* A[3];
  const bf16* Bt[3];
  const float* bias[3];
  void* C[3];
  int vtz;          // which z writes transposed output (-1: none)
  bf16* Cvt;        // [N][M] transposed output for z == vtz
  float oscale[3];  // per-z output scale (e.g. fold softmax scale into Q)
};

template <bool OUT_BF16, int BN>
__device__ __forceinline__ void gemm_core(const Gemm3& g, int M, int N, int K, int bx) {
  constexpr int NB = BN / 32;       // 16-col blocks per wave (wave covers BN/2 cols)
  const int nx = N / BN, nyl = (M >> 7) >> 3;
  const int xcd = bx & 7;
  const int ib = bx >> 3;
  const int z = ib / (nx * nyl);
  const int r = ib - z * (nx * nyl);
  const int x = r / nyl;
  const int yl = r - x * nyl;
  const int y = xcd * nyl + yl;

  const bf16* __restrict__ A  = g.A[z];
  const bf16* __restrict__ Bt = g.Bt[z];
  const float* bias = g.bias[z];
  void* C = g.C[z];
  const float osc = g.oscale[z];

  __shared__ bf16 As[128 * 64];
  __shared__ bf16 Bs[BN * 64];

  const int tid = threadIdx.x;
  const int lane = tid & 63;
  const int w = tid >> 6;
  const int wr = w >> 1, wc = w & 1;
  const int l16 = lane & 15, kg = lane >> 4;
  const int m0 = y * 128, n0 = x * BN;

  f32x4 acc[4][NB] = {};

  for (int k0 = 0; k0 < K; k0 += 64) {
#pragma unroll
    for (int i = 0; i < 4; ++i) {
      const int gc = i * 256 + tid;
      const int row = gc >> 3, ch = gc & 7;
      const int lch = ch ^ (row & 7);
      gld_lds16(A + (size_t)(m0 + row) * K + k0 + lch * 8,
                (char*)As + i * 4096 + w * 1024);
    }
#pragma unroll
    for (int i = 0; i < NB; ++i) {
      const int gc = i * 256 + tid;
      const int row = gc >> 3, ch = gc & 7;
      const int lch = ch ^ (row & 7);
      gld_lds16(Bt + (size_t)(n0 + row) * K + k0 + lch * 8,
                (char*)Bs + i * 4096 + w * 1024);
    }
    __syncthreads();
#pragma unroll
    for (int kk = 0; kk < 2; ++kk) {
      const int cc = kk * 4 + kg;
      bf16x8 af[4], bfr[NB];
#pragma unroll
      for (int m = 0; m < 4; ++m) {
        const int rr = wr * 64 + m * 16 + l16;
        af[m] = *(const bf16x8*)((const char*)As + rr * 128 + ((cc ^ (rr & 7)) << 4));
      }
#pragma unroll
      for (int n = 0; n < NB; ++n) {
        const int rn = wc * (BN / 2) + n * 16 + l16;
        bfr[n] = *(const bf16x8*)((const char*)Bs + rn * 128 + ((cc ^ (rn & 7)) << 4));
      }
#pragma unroll
      for (int m = 0; m < 4; ++m)
#pragma unroll
        for (int n = 0; n < NB; ++n)
          acc[m][n] = MFMA16(af[m], bfr[n], acc[m][n]);
    }
    __syncthreads();
  }

  if (z == g.vtz) {
    // transposed write: Cvt[col][row], pack 4 consecutive rows (8B store)
#pragma unroll
    for (int m = 0; m < 4; ++m) {
      const int row0 = m0 + wr * 64 + m * 16 + kg * 4;
#pragma unroll
      for (int n = 0; n < NB; ++n) {
        const int col = n0 + wc * (BN / 2) + n * 16 + l16;
        const float bb = bias ? bias[col] : 0.f;
        bf16x4 pk;
#pragma unroll
        for (int i = 0; i < 4; ++i) pk[i] = (bf16)((acc[m][n][i] + bb) * osc);
        *(bf16x4*)(g.Cvt + (size_t)col * M + row0) = pk;
      }
    }
    return;
  }

#pragma unroll
  for (int m = 0; m < 4; ++m) {
    const int row0 = m0 + wr * 64 + m * 16 + kg * 4;
#pragma unroll
    for (int n = 0; n < NB; ++n) {
      const int col = n0 + wc * (BN / 2) + n * 16 + l16;
      const float bb = bias ? bias[col] : 0.f;
#pragma unroll
      for (int i = 0; i < 4; ++i) {
        float val = (acc[m][n][i] + bb) * osc;
        if (OUT_BF16) ((bf16*)C)[(size_t)(row0 + i) * N + col] = (bf16)val;
        else          ((float*)C)[(size_t)(row0 + i) * N + col] = val;
      }
    }
  }
}

template <bool OUT_BF16, int BN>
__global__ __launch_bounds__(256) void gemm_bt(Gemm3 g, int M, int N, int K) {
  gemm_core<OUT_BF16, BN>(g, M, N, K, blockIdx.x);
}

// ---------------- combine GEMM + q/k/v cast in ONE launch ---------------------
struct CastQKV { const float* src[3]; bf16* dst[3]; };
__global__ __launch_bounds__(256) void combine_cast(Gemm3 g, CastQKV c) {
  if ((int)blockIdx.x < 384) {
    gemm_core<true, 64>(g, 1024, 1024, 1024, blockIdx.x);
  } else {
    const int cb = blockIdx.x - 384;
#pragma unroll
    for (int it = 0; it < 12; ++it) {
      const int chunk = (it * 512 + cb) * 256 + (int)threadIdx.x;  // < 1572864
      const int arr = chunk >> 19;
      const size_t off = (size_t)(chunk & 524287) << 3;
      const float* __restrict__ s = c.src[arr];
      bf16* __restrict__ d = c.dst[arr];
      float4 x = *(const float4*)(s + off);
      float4 y = *(const float4*)(s + off + 4);
      bf16x8 o;
      o[0] = (bf16)x.x; o[1] = (bf16)x.y; o[2] = (bf16)x.z; o[3] = (bf16)x.w;
      o[4] = (bf16)y.x; o[5] = (bf16)y.y; o[6] = (bf16)y.z; o[7] = (bf16)y.w;
      *(bf16x8*)(d + off) = o;
    }
  }
}

// ---------------- flash attention (causal, no-max softmax, packed P) ----------
// R22/R24 base (40.4us) + HOISTED DUAL-SUB QK: both 64-key subs' QK^T MFMAs
// issue back-to-back before any softmax/PV, so exp(s0) VALU overlaps QK(s1)
// MFMA retirement and PV(s0) queues behind it in the matrix pipe (within-wave
// MFMA/VALU overlap). Shared P buffer stays safe: per-wave DS ops execute in
// issue order (P-write(s1) after PV(s0) reads). +16 VGPR (sc0+sc1 live).
#define SEQL 2048
__global__ __launch_bounds__(512) void attn_flash(const bf16* __restrict__ qh,
                                                  const bf16* __restrict__ kh,
                                                  const bf16* __restrict__ vt,
                                                  bf16* __restrict__ conc) {
  const int bx = blockIdx.x;
  const int xcd = bx & 7, j = bx >> 3;
  const int half = j >> 5, jj = j & 31;
  const int bh = xcd * 4 + (jj >> 3);
  const int tq = jj & 7;
  const int rb = half ? tq : 15 - tq;
  const int b = bh >> 4, h = bh & 15;
  const int tid = threadIdx.x, lane = tid & 63, w = tid >> 6;
  const int wh = w >> 2;                 // which 64-row half
  const int l16 = lane & 15, kg = lane >> 4;

  __shared__ bf16 KsB[2 * 8192];  // 2 bufs x 128 rows x 64 elems (swz), 32KB
  __shared__ bf16 VsB[2 * 8192];  // 2 bufs x 64 d x 128 s (swz), 32KB
  __shared__ bf16 Ps[8 * 1024];   // per-wave 16x64 (swz), shared across subs, 16KB

  char* Psw = (char*)Ps + w * 2048;
  const size_t kvbase = ((size_t)(b * SEQL)) * 1024 + h * 64;
  const bf16* vbase = vt + ((size_t)(h * 64)) * 4096 + b * SEQL;

  auto stage = [&](int buf, int p) {
    const int j0 = p * 128;
#pragma unroll
    for (int c = 0; c < 2; ++c) {
      const int idx = c * 512 + tid;
      const int kr = idx >> 3;
      // physical row kr holds key tau(kr): bijective within each 64-group
      const int kkey = (kr & 64) + ((kr & 15) << 2) + ((kr & 63) >> 4);
      const int kch = (idx & 7) ^ (kr & 7);
      gld_lds16(kh + kvbase + (size_t)(j0 + kkey) * 1024 + kch * 8,
                (char*)KsB + buf * 16384 + c * 8192 + w * 1024);
      const int vr = idx >> 4;
      const int vch = (idx & 15) ^ (vr & 15);
      gld_lds16(vbase + (size_t)vr * 4096 + j0 + vch * 8,
                (char*)VsB + buf * 16384 + c * 8192 + w * 1024);
    }
  };

  bf16x8 onesv;
#pragma unroll
  for (int i = 0; i < 8; ++i) onesv[i] = (bf16)1.0f;

  const int q0a = rb * 128;
  const int npairs = rb + 1;
  const int myrow0 = q0a + wh * 64 + (w & 3) * 16;  // wave's 16-row base
  const int rowmax = q0a + wh * 64 + 63;            // wave-half's last q row

  const int qrow = myrow0 + l16;
  const size_t qoff = ((size_t)(b * SEQL) + qrow) * 1024 + h * 64;
  const bf16x8 qf0 = *(const bf16x8*)(qh + qoff + kg * 8);
  const bf16x8 qf1 = *(const bf16x8*)(qh + qoff + 32 + kg * 8);

  // hoisted LDS address components (bit-identities verified):
  const int swzk  = (kg ^ (l16 & 7)) << 4;   // K/P swizzle; kb/s-invariant
  const int swzk1 = swzk ^ 64;               // c -> c+4 flips bit 6
  const int swzv  = (kg ^ l16) << 4;         // V swizzle base (rr&15 == l16)
  const char* const pA0 = Psw + l16 * 128 + swzk;    // P-read kc=0
  const char* const pA1 = Psw + l16 * 128 + swzk1;   // P-read kc=1
  const int wsw = (((l16 >> 1) ^ ((kg & 1) * 4)) << 4) | ((l16 & 1) << 3);
  char* wAddr[4];
#pragma unroll
  for (int i = 0; i < 4; ++i)
    wAddr[i] = Psw + kg * 512 + i * 128 + (wsw ^ (i * 16));

  f32x4 acc[4] = {};
  f32x4 accl = {};

  stage(0, 0);
  __syncthreads();

  for (int p = 0; p < npairs; ++p) {
    const int cur = p & 1;
    if (p + 1 < npairs) stage(cur ^ 1, p + 1);

    const char* Kb = (const char*)KsB + cur * 16384;
    const char* Vb = (const char*)VsB + cur * 16384;
    const char* kR0 = Kb + l16 * 128 + swzk;
    const char* kR1 = Kb + l16 * 128 + swzk1;
    const char* vR  = Vb + l16 * 256;

    const bool act1 = (p * 128 + 64) <= rowmax;  // sub1 active? (sub0 always is)

    // ---- QK for BOTH subs up front (16 independent MFMAs fill the pipe)
    f32x4 sc0[4], sc1[4];
    __builtin_amdgcn_s_setprio(1);
#pragma unroll
    for (int kb = 0; kb < 4; ++kb) {
      bf16x8 kf0 = *(const bf16x8*)(kR0 + kb * 2048);
      bf16x8 kf1 = *(const bf16x8*)(kR1 + kb * 2048);
      f32x4 cfr = {};
      cfr = MFMA16(qf0, kf0, cfr);
      sc0[kb] = MFMA16(qf1, kf1, cfr);
    }
    if (act1) {
#pragma unroll
      for (int kb = 0; kb < 4; ++kb) {
        bf16x8 kf0 = *(const bf16x8*)(kR0 + 8192 + kb * 2048);
        bf16x8 kf1 = *(const bf16x8*)(kR1 + 8192 + kb * 2048);
        f32x4 cfr = {};
        cfr = MFMA16(qf0, kf0, cfr);
        sc1[kb] = MFMA16(qf1, kf1, cfr);
      }
    }
    __builtin_amdgcn_s_setprio(0);

    // ---- sub 0: mask + exp + packed P-store + PV
    {
      const int j0 = p * 128;
      if (j0 + 63 > myrow0) {
#pragma unroll
        for (int kb = 0; kb < 4; ++kb) {
          const int key = j0 + l16 * 4 + kb;
#pragma unroll
          for (int i = 0; i < 4; ++i)
            if (key > myrow0 + kg * 4 + i) sc0[kb][i] = -1e9f;
        }
      }
#pragma unroll
      for (int i = 0; i < 4; ++i) {
        bf16x4 pk;
#pragma unroll
        for (int kb = 0; kb < 4; ++kb)
          pk[kb] = (bf16)__builtin_exp2f(sc0[kb][i]);
        *(bf16x4*)(wAddr[i]) = pk;
      }
      __builtin_amdgcn_s_setprio(1);
#pragma unroll
      for (int kc = 0; kc < 2; ++kc) {
        bf16x8 pf = *(const bf16x8*)(kc == 0 ? pA0 : pA1);
        accl = MFMA16(pf, onesv, accl);
        const char* vA = vR + (swzv ^ (kc * 64));
#pragma unroll
        for (int nb = 0; nb < 4; ++nb) {
          bf16x8 vf = *(const bf16x8*)(vA + nb * 4096);
          acc[nb] = MFMA16(pf, vf, acc[nb]);
        }
      }
      __builtin_amdgcn_s_setprio(0);
    }

    // ---- sub 1 (reuses the per-wave P buffer; per-wave DS ops are in-order)
    if (act1) {
      const int j0 = p * 128 + 64;
      if (j0 + 63 > myrow0) {
#pragma unroll
        for (int kb = 0; kb < 4; ++kb) {
          const int key = j0 + l16 * 4 + kb;
#pragma unroll
          for (int i = 0; i < 4; ++i)
            if (key > myrow0 + kg * 4 + i) sc1[kb][i] = -1e9f;
        }
      }
#pragma unroll
      for (int i = 0; i < 4; ++i) {
        bf16x4 pk;
#pragma unroll
        for (int kb = 0; kb < 4; ++kb)
          pk[kb] = (bf16)__builtin_exp2f(sc1[kb][i]);
        *(bf16x4*)(wAddr[i]) = pk;
      }
      __builtin_amdgcn_s_setprio(1);
#pragma unroll
      for (int kc = 0; kc < 2; ++kc) {
        bf16x8 pf = *(const bf16x8*)(kc == 0 ? pA0 : pA1);
        accl = MFMA16(pf, onesv, accl);
        const char* vA = vR + (swzv ^ (128 + kc * 64));
#pragma unroll
        for (int nb = 0; nb < 4; ++nb) {
          bf16x8 vf = *(const bf16x8*)(vA + nb * 4096);
          acc[nb] = MFMA16(pf, vf, acc[nb]);
        }
      }
      __builtin_amdgcn_s_setprio(0);
    }
    __syncthreads();
  }

#pragma unroll
  for (int nb = 0; nb < 4; ++nb)
#pragma unroll
    for (int i = 0; i < 4; ++i) {
      const float val = acc[nb][i] / accl[i];
      const int row = myrow0 + kg * 4 + i;
      conc[((size_t)(b * SEQL) + row) * 1024 + h * 64 + nb * 16 + l16] = (bf16)val;
    }
}

extern "C" void kernel_launch(void* const* d_in, const int* in_sizes, int n_in,
                              void* d_out, int out_size, void* d_ws, size_t ws_size,
                              hipStream_t stream) {
  (void)in_sizes; (void)n_in; (void)out_size; (void)ws_size;
  const float* q    = (const float*)d_in[0];
  const float* k    = (const float*)d_in[1];
  const float* v    = (const float*)d_in[2];
  // d_in[3] = mask (causal by construction; not needed)
  const float* W_in = (const float*)d_in[4];
  const float* b_in = (const float*)d_in[5];
  const float* Wq = (const float*)d_in[6];  const float* bq = (const float*)d_in[7];
  const float* Wk = (const float*)d_in[8];  const float* bk = (const float*)d_in[9];
  const float* Wv = (const float*)d_in[10]; const float* bv = (const float*)d_in[11];
  const float* Wo = (const float*)d_in[12]; const float* bo = (const float*)d_in[13];

  const size_t SA = (size_t)4096 * 1024;  // activation elems
  const size_t SW = (size_t)1024 * 1024;  // weight elems
  bf16* p = (bf16*)d_ws;
  bf16* qb  = p; p += SA;
  bf16* kb  = p; p += SA;
  bf16* vb  = p; p += SA;
  bf16* qhb = p; p += SA;
  bf16* khb = p; p += SA;
  bf16* vhb = p; p += SA;                 // unused (V goes to vtb)
  bf16* Wib = p; p += SW;
  bf16* Wtq = p; p += SW;
  bf16* Wtk = p; p += SW;
  bf16* Wtv = p; p += SW;
  bf16* Wto = p; p += SW;
  bf16* Wc0 = p; p += SW;
  bf16* Wc1 = p; p += SW;
  bf16* Wc2 = p; p += SW;
  float* bc = (float*)p;       // 3 * 1024 fp32
  bf16* conc = qb;             // reuse qb after projections
  bf16* vtb = Wib;             // [1024][4096]; aliases Wib..Wtv (dead after combine GEMM)

  // stage 1: all independent prep in one launch
  PrepArgs pa;
  pa.W_in = W_in; pa.Wib = Wib;
  pa.Wsrc[0] = Wq; pa.Wdst[0] = Wtq;
  pa.Wsrc[1] = Wk; pa.Wdst[1] = Wtk;
  pa.Wsrc[2] = Wv; pa.Wdst[2] = Wtv;
  pa.Wsrc[3] = Wo; pa.Wdst[3] = Wto;
  pa.b_in = b_in;
  pa.Wz[0] = Wq; pa.Wz[1] = Wk; pa.Wz[2] = Wv;
  pa.bz[0] = bq; pa.bz[1] = bk; pa.bz[2] = bv;
  pa.bc = bc;
  prep_all<<<dim3(4656), 256, 0, stream>>>(pa);

  // stage 2: combine weights (Wc_t = (W_in*W)^T) + q/k/v cast, one launch
  Gemm3 gc;
  gc.A[0] = Wtq; gc.A[1] = Wtk; gc.A[2] = Wtv;
  gc.Bt[0] = Wib; gc.Bt[1] = Wib; gc.Bt[2] = Wib;
  gc.bias[0] = nullptr; gc.bias[1] = nullptr; gc.bias[2] = nullptr;
  gc.C[0] = Wc0; gc.C[1] = Wc1; gc.C[2] = Wc2;
  gc.vtz = -1; gc.Cvt = nullptr;
  gc.oscale[0] = 1.f; gc.oscale[1] = 1.f; gc.oscale[2] = 1.f;
  CastQKV cq;
  cq.src[0] = q; cq.src[1] = k; cq.src[2] = v;
  cq.dst[0] = qb; cq.dst[1] = kb; cq.dst[2] = vb;
  combine_cast<<<dim3(896), 256, 0, stream>>>(gc, cq);

  // stage 3: head projections (bf16 A); Q pre-scaled by log2(e)/8 (softmax
  // scale folded in); V written transposed into vtb[1024][4096]
  Gemm3 gp;
  gp.A[0] = qb; gp.A[1] = kb; gp.A[2] = vb;
  gp.Bt[0] = Wc0; gp.Bt[1] = Wc1; gp.Bt[2] = Wc2;
  gp.bias[0] = bc; gp.bias[1] = bc + 1024; gp.bias[2] = bc + 2048;
  gp.C[0] = qhb; gp.C[1] = khb; gp.C[2] = vhb;
  gp.vtz = 2; gp.Cvt = vtb;
  gp.oscale[0] = 0.18033688011112042f;  // log2(e)/8
  gp.oscale[1] = 1.f; gp.oscale[2] = 1.f;
  gemm_bt<true, 128><<<dim3(768), 256, 0, stream>>>(gp, 4096, 1024, 1024);

  attn_flash<<<dim3(512), 512, 0, stream>>>(qhb, khb, vtb, conc);

  // output projection -> fp32 d_out
  Gemm3 gf;
  gf.A[0] = conc; gf.A[1] = conc; gf.A[2] = conc;
  gf.Bt[0] = Wto; gf.Bt[1] = Wto; gf.Bt[2] = Wto;
  gf.bias[0] = bo; gf.bias[1] = bo; gf.bias[2] = bo;
  gf.C[0] = d_out; gf.C[1] = d_out; gf.C[2] = d_out;
  gf.vtz = -1; gf.Cvt = nullptr;
  gf.oscale[0] = 1.f; gf.oscale[1] = 1.f; gf.oscale[2] = 1.f;
  gemm_bt<false, 64><<<dim3(512), 256, 0, stream>>>(gf, 4096, 1024, 1024);
}